// Round 7
// baseline (99.292 us; speedup 1.0000x reference)
//
#include <hip/hip_runtime.h>
#include <hip/hip_bf16.h>
#include <math.h>

typedef __bf16 bf16x8 __attribute__((ext_vector_type(8)));
typedef __bf16 bf16x2 __attribute__((ext_vector_type(2)));
typedef float  floatx16 __attribute__((ext_vector_type(16)));
typedef unsigned u32x4 __attribute__((ext_vector_type(4)));

// Workspace layout (bytes):
//   Kq    bf16 [2][8192][16]        offset 0        (512 KB)  scaled by sqrt(log2 e)
//   Vswz  bf16 [2][8192][32]        offset 524288   (1 MB)    P-natural-order B-frag swizzle
//   Opart bf16 [2*8192][16][32]     offset 1572864  (16.8 MB) normalized ratios r_s = O_s/l_s
//   Lpart f32  [2*8192][16]         after Opart     (1 MB)
#define KQ_ELEMS (2 * 8192 * 16)
#define OPART_OFF 1572864
#define SQRT_LOG2E 1.2011224087864498f
#define LSPLIT 4

// ---------------- Kernel A: projections ----------------
// v7 Vswz layout (verified): B-fragment in P's NATURAL slot order -> flash needs
// ZERO cross-lane ops. Per 32-j tile (f = jl>>4, jj = jl&15):
//   h = (jj>>2)&1 ; idx = (jj&3) | (((jj>>3)&1)<<2)
//   flat = jt*1024 + f*512 + h*256 + c*8 + idx
__global__ __launch_bounds__(512) void proj_kernel(
    const float* __restrict__ in, const float* __restrict__ W1,
    const float* __restrict__ b1, const float* __restrict__ W2,
    const float* __restrict__ b2,
    __hip_bfloat16* __restrict__ Kq, __hip_bfloat16* __restrict__ Vswz)
{
    __shared__ float Xs[32][32];
    __shared__ float W1s[16 * 32];
    __shared__ float W2s[32 * 32];
    const int t = threadIdx.x;
    const int bid = blockIdx.x;       // 0..511
    const int b = bid >> 8;
    const int hw = bid & 255;

    {
        int l = t >> 4, cs = (t & 15) * 2;
        float2 v = *(const float2*)(in + (((size_t)b * 32 + l) * 256 + hw) * 32 + cs);
        *(float2*)&Xs[l][cs] = v;
    }
    if (t < 128) *(float4*)&W1s[t * 4] = *(const float4*)(W1 + t * 4);
    if (t < 256) *(float4*)&W2s[t * 4] = *(const float4*)(W2 + t * 4);
    __syncthreads();

    const int c = t & 31;
    const int g = t >> 5;             // 0..15

    {
        int o = g;                    // 0..15
        float a0 = b1[o], a1 = 0.f;
#pragma unroll
        for (int l = 0; l < 16; ++l) {
            a0 += W1s[o * 32 + l] * Xs[l][c];
            a1 += W1s[o * 32 + 16 + l] * Xs[16 + l][c];
        }
        float acc = a0 + a1;
        int k = c >> 1;
        int i = (c & 1) * 4096 + o * 256 + hw;
        Kq[((size_t)b * 8192 + i) * 16 + k] = __float2bfloat16(acc * SQRT_LOG2E);
    }
#pragma unroll
    for (int oo = 0; oo < 2; ++oo) {
        int o = g * 2 + oo;           // 0..31
        float a0 = b2[o], a1 = 0.f;
#pragma unroll
        for (int l = 0; l < 16; ++l) {
            a0 += W2s[o * 32 + l] * Xs[l][c];
            a1 += W2s[o * 32 + 16 + l] * Xs[16 + l][c];
        }
        float acc = a0 + a1;
        // position j = o*256 + hw, channel c; P-natural-order swizzle (v7):
        int jt = o * 8 + (hw >> 5);          // j >> 5
        int f  = (hw >> 4) & 1;              // frag: jl 0..15 -> 0, 16..31 -> 1
        int hh = (hw >> 2) & 1;              // owner half
        int idx = (hw & 3) | (((hw >> 3) & 1) << 2);
        Vswz[(size_t)b * 262144 + jt * 1024 + f * 512 + hh * 256 + c * 8 + idx] =
            __float2bfloat16(acc);
    }
}

// ---------------- Kernel B: flash attention, LDS-free, bf16 normalized partials ----------------
// v8: TWO i-tiles per wave (64 i-rows: bq0/oa0 + bq1/oa1). Same ak/vb loads feed two
// independent S->exp->PV chains -> 8 ILP chains/SIMD (was 4) and K/V load traffic
// halved. R6 arithmetic: 553 cyc/iter-slot vs ~160 cyc pipe-busy sum = latency-bound;
// more chains is the direct attack. LSPLIT 3->4 keeps grid at 1024 blocks (4 blk/CU,
// 4 waves/SIMD under the (256,4) cap). #pragma unroll 1 pins register pressure
// (~124 VGPR est., cap 128; a spill here is diagnostic -> fallback (256,3)).
// Keeps: P-natural V-swizzle (zero cross-lane), single-acc-per-tile, native x16
// MFMAs, depth-1 prefetch, streaming stores (NOT atomics: RMW pinned ~44us).
__global__ __launch_bounds__(256, 4) void flash_kernel(
    const __hip_bfloat16* __restrict__ Kq, const __hip_bfloat16* __restrict__ Vswz,
    __hip_bfloat16* __restrict__ Opart, float* __restrict__ Lpart)
{
    const int t = threadIdx.x;
    const int lane = t & 63;
    const int wv = t >> 6;            // 0..3
    const int m = lane & 31;
    const int h = lane >> 5;          // 0/1

    const int bid = blockIdx.x;
    const int s = bid & ((1 << LSPLIT) - 1);
    const int itile = (bid >> LSPLIT) & 31;     // 32 i-tiles of 256 rows
    const int b = bid >> (LSPLIT + 5);
    const int i0 = itile * 256 + wv * 64;       // this wave: rows [i0, i0+64)
    const int niter = (8192 >> LSPLIT) >> 5;    // 16 tiles of 32 j
    const int jt0 = s * niter;

    const __hip_bfloat16* Kb = Kq + (size_t)b * 8192 * 16;
    const __hip_bfloat16* Vb = Vswz + (size_t)b * 262144 + h * 256 + m * 8;

    // Q B-frags for the two i-subtiles
    const bf16x8 bq0 = *(const bf16x8*)(Kb + (size_t)(i0 + m) * 16 + h * 8);
    const bf16x8 bq1 = *(const bf16x8*)(Kb + (size_t)(i0 + 32 + m) * 16 + h * 8);

    floatx16 oa0 = {}, oa1 = {};
    float lA0 = 0.f, lA1 = 0.f, lA2 = 0.f, lA3 = 0.f;
    float lB0 = 0.f, lB1 = 0.f, lB2 = 0.f, lB3 = 0.f;

    // ---- software pipeline: preload tile jt0 ----
    bf16x8 ak = *(const bf16x8*)(Kb + (size_t)(jt0 * 32 + m) * 16 + h * 8);
    bf16x8 vb0 = *(const bf16x8*)(Vb + (size_t)jt0 * 1024 + 0);
    bf16x8 vb1 = *(const bf16x8*)(Vb + (size_t)jt0 * 1024 + 512);

#pragma unroll 1
    for (int it = 0; it < niter; ++it) {
        const bf16x8 cak = ak;
        const bf16x8 cv0 = vb0, cv1 = vb1;
        if (it + 1 < niter) {
            const int jn = jt0 + it + 1;
            ak  = *(const bf16x8*)(Kb + (size_t)(jn * 32 + m) * 16 + h * 8);
            vb0 = *(const bf16x8*)(Vb + (size_t)jn * 1024 + 0);
            vb1 = *(const bf16x8*)(Vb + (size_t)jn * 1024 + 512);
        }

        // S^T(32j x 32i) = K(A) x Q(B), K=16 exact — two independent chains
        floatx16 sc0 = __builtin_amdgcn_mfma_f32_32x32x16_bf16(cak, bq0, (floatx16){}, 0, 0, 0);
        floatx16 sc1 = __builtin_amdgcn_mfma_f32_32x32x16_bf16(cak, bq1, (floatx16){}, 0, 0, 0);

        // P = 2^S ; cvt_pk pairs ARE the A-frag dwords under the v7 V-swizzle.
#pragma unroll
        for (int half = 0; half < 2; ++half) {
            u32x4 pau0, pau1;
#pragma unroll
            for (int gg = 0; gg < 2; ++gg) {
                const int g = half * 2 + gg;
                {   // tile A
                    float e0 = __builtin_amdgcn_exp2f(sc0[4 * g + 0]);
                    float e1 = __builtin_amdgcn_exp2f(sc0[4 * g + 1]);
                    float e2 = __builtin_amdgcn_exp2f(sc0[4 * g + 2]);
                    float e3 = __builtin_amdgcn_exp2f(sc0[4 * g + 3]);
                    lA0 += e0; lA1 += e1; lA2 += e2; lA3 += e3;
#if defined(__has_builtin) && __has_builtin(__builtin_amdgcn_cvt_pk_bf16_f32)
                    bf16x2 pk0 = __builtin_amdgcn_cvt_pk_bf16_f32(e0, e1);
                    bf16x2 pk1 = __builtin_amdgcn_cvt_pk_bf16_f32(e2, e3);
#else
                    bf16x2 pk0 = {(__bf16)e0, (__bf16)e1};
                    bf16x2 pk1 = {(__bf16)e2, (__bf16)e3};
#endif
                    pau0[gg * 2 + 0] = __builtin_bit_cast(unsigned, pk0);
                    pau0[gg * 2 + 1] = __builtin_bit_cast(unsigned, pk1);
                }
                {   // tile B
                    float e0 = __builtin_amdgcn_exp2f(sc1[4 * g + 0]);
                    float e1 = __builtin_amdgcn_exp2f(sc1[4 * g + 1]);
                    float e2 = __builtin_amdgcn_exp2f(sc1[4 * g + 2]);
                    float e3 = __builtin_amdgcn_exp2f(sc1[4 * g + 3]);
                    lB0 += e0; lB1 += e1; lB2 += e2; lB3 += e3;
#if defined(__has_builtin) && __has_builtin(__builtin_amdgcn_cvt_pk_bf16_f32)
                    bf16x2 pk0 = __builtin_amdgcn_cvt_pk_bf16_f32(e0, e1);
                    bf16x2 pk1 = __builtin_amdgcn_cvt_pk_bf16_f32(e2, e3);
#else
                    bf16x2 pk0 = {(__bf16)e0, (__bf16)e1};
                    bf16x2 pk1 = {(__bf16)e2, (__bf16)e3};
#endif
                    pau1[gg * 2 + 0] = __builtin_bit_cast(unsigned, pk0);
                    pau1[gg * 2 + 1] = __builtin_bit_cast(unsigned, pk1);
                }
            }
            const bf16x8 cv = half ? cv1 : cv0;
            oa0 = __builtin_amdgcn_mfma_f32_32x32x16_bf16(__builtin_bit_cast(bf16x8, pau0), cv, oa0, 0, 0, 0);
            oa1 = __builtin_amdgcn_mfma_f32_32x32x16_bf16(__builtin_bit_cast(bf16x8, pau1), cv, oa1, 0, 0, 0);
        }
    }

    // split-partial row-sums for the two tiles (this lane's query = i0[+32]+m)
    float la = (lA0 + lA1) + (lA2 + lA3);
    la += __shfl_xor(la, 32);
    float lb = (lB0 + lB1) + (lB2 + lB3);
    lb += __shfl_xor(lb, 32);
    const float rA = __builtin_amdgcn_rcpf(la);
    const float rB = __builtin_amdgcn_rcpf(lb);

    // store normalized ratios r_s = O_s / l_s as bf16.
    // reg r -> row i_loc=(r&3)+8*(r>>2)+4h, col c=m ; l for row iloc lives in lane iloc
#pragma unroll
    for (int r = 0; r < 16; ++r) {
        int iloc = (r & 3) + 8 * (r >> 2) + 4 * h;
        float lrA = __shfl(rA, iloc);
        float lrB = __shfl(rB, iloc);
        size_t rowA = (size_t)b * 8192 + i0 + iloc;
        Opart[((rowA << LSPLIT) | s) * 32 + m] = __float2bfloat16(oa0[r] * lrA);
        Opart[(((rowA + 32) << LSPLIT) | s) * 32 + m] = __float2bfloat16(oa1[r] * lrB);
    }
    if (h == 0) {
        Lpart[(((size_t)b * 8192 + i0 + m) << LSPLIT) | s] = la;
        Lpart[(((size_t)b * 8192 + i0 + 32 + m) << LSPLIT) | s] = lb;
    }
}

// ---------------- Kernel C: weighted combine + epilogue ----------------
// out = (sum_s l_s * r_s) / (sum_s l_s) * gamma + in   (16 splits, LSPLIT=4)
__global__ __launch_bounds__(256) void combine_kernel(
    const unsigned short* __restrict__ Opart, const float* __restrict__ Lpart,
    const float* __restrict__ in, const float* __restrict__ gamma,
    float* __restrict__ out)
{
    const int gid = blockIdx.x * 256 + threadIdx.x;   // 0..262143
    const int row = gid >> 4;                          // 0..16383
    const int c2 = (gid & 15) * 2;
    const unsigned short* op = Opart + (((size_t)row << LSPLIT)) * 32 + c2;
    const float* lp = Lpart + ((size_t)row << LSPLIT);
    float ls[1 << LSPLIT];
#pragma unroll
    for (int q = 0; q < (1 << LSPLIT) / 4; ++q) {
        float4 lv = *(const float4*)(lp + q * 4);
        ls[q * 4 + 0] = lv.x; ls[q * 4 + 1] = lv.y;
        ls[q * 4 + 2] = lv.z; ls[q * 4 + 3] = lv.w;
    }
    float ax = 0.f, ay = 0.f;
    float lsum = 0.f;
#pragma unroll
    for (int s = 0; s < (1 << LSPLIT); ++s) {
        ushort2 u = *(const ushort2*)(op + s * 32);
        float l = ls[s];
        ax += l * __uint_as_float((unsigned)u.x << 16);
        ay += l * __uint_as_float((unsigned)u.y << 16);
        lsum += l;
    }
    const size_t base = (size_t)row * 32 + c2;
    float2 x = *(const float2*)(in + base);
    const float gl = gamma[0] / lsum;
    float2 r;
    r.x = ax * gl + x.x;
    r.y = ay * gl + x.y;
    *(float2*)(out + base) = r;
}

extern "C" void kernel_launch(void* const* d_in, const int* in_sizes, int n_in,
                              void* d_out, int out_size, void* d_ws, size_t ws_size,
                              hipStream_t stream) {
    const float* in = (const float*)d_in[0];
    const float* W1 = (const float*)d_in[1];
    const float* b1 = (const float*)d_in[2];
    const float* W2 = (const float*)d_in[3];
    const float* b2 = (const float*)d_in[4];
    const float* gamma = (const float*)d_in[5];
    float* out = (float*)d_out;

    __hip_bfloat16* Kq = (__hip_bfloat16*)d_ws;
    __hip_bfloat16* Vswz = Kq + KQ_ELEMS;
    __hip_bfloat16* Opart = (__hip_bfloat16*)((char*)d_ws + OPART_OFF);
    float* Lpart = (float*)(Opart + ((size_t)16384 << LSPLIT) * 32);

    proj_kernel<<<512, 512, 0, stream>>>(in, W1, b1, W2, b2, Kq, Vswz);
    flash_kernel<<<2 * 32 * (1 << LSPLIT), 256, 0, stream>>>(Kq, Vswz, Opart, Lpart);
    combine_kernel<<<1024, 256, 0, stream>>>((const unsigned short*)Opart, Lpart, in, gamma, out);
}

// Round 8
// 98.133 us; speedup vs baseline: 1.0118x; 1.0118x over previous
//
#include <hip/hip_runtime.h>
#include <hip/hip_bf16.h>
#include <math.h>

typedef __bf16 bf16x8 __attribute__((ext_vector_type(8)));
typedef __bf16 bf16x2 __attribute__((ext_vector_type(2)));
typedef float  floatx16 __attribute__((ext_vector_type(16)));
typedef unsigned u32x4 __attribute__((ext_vector_type(4)));

// Workspace layout (bytes):
//   Kq    bf16 [2][8192][16]        offset 0        (512 KB)  scaled by sqrt(log2 e)
//   Vswz  bf16 [2][8192][32]        offset 524288   (1 MB)    P-natural-order B-frag swizzle
//   Opart bf16 [2*8192][16][32]     offset 1572864  (16.8 MB) normalized ratios r_s = O_s/l_s
//   Lpart f32  [2*8192][16]         after Opart     (1 MB)
#define KQ_ELEMS (2 * 8192 * 16)
#define OPART_OFF 1572864
#define SQRT_LOG2E 1.2011224087864498f
#define LSPLIT 4

// ---------------- Kernel A: projections ----------------
// v7 Vswz layout (verified): B-fragment in P's NATURAL slot order -> flash needs
// ZERO cross-lane ops. Per 32-j tile (f = jl>>4, jj = jl&15):
//   h = (jj>>2)&1 ; idx = (jj&3) | (((jj>>3)&1)<<2)
//   flat = jt*1024 + f*512 + h*256 + c*8 + idx
__global__ __launch_bounds__(512) void proj_kernel(
    const float* __restrict__ in, const float* __restrict__ W1,
    const float* __restrict__ b1, const float* __restrict__ W2,
    const float* __restrict__ b2,
    __hip_bfloat16* __restrict__ Kq, __hip_bfloat16* __restrict__ Vswz)
{
    __shared__ float Xs[32][32];
    __shared__ float W1s[16 * 32];
    __shared__ float W2s[32 * 32];
    const int t = threadIdx.x;
    const int bid = blockIdx.x;       // 0..511
    const int b = bid >> 8;
    const int hw = bid & 255;

    {
        int l = t >> 4, cs = (t & 15) * 2;
        float2 v = *(const float2*)(in + (((size_t)b * 32 + l) * 256 + hw) * 32 + cs);
        *(float2*)&Xs[l][cs] = v;
    }
    if (t < 128) *(float4*)&W1s[t * 4] = *(const float4*)(W1 + t * 4);
    if (t < 256) *(float4*)&W2s[t * 4] = *(const float4*)(W2 + t * 4);
    __syncthreads();

    const int c = t & 31;
    const int g = t >> 5;             // 0..15

    {
        int o = g;                    // 0..15
        float a0 = b1[o], a1 = 0.f;
#pragma unroll
        for (int l = 0; l < 16; ++l) {
            a0 += W1s[o * 32 + l] * Xs[l][c];
            a1 += W1s[o * 32 + 16 + l] * Xs[16 + l][c];
        }
        float acc = a0 + a1;
        int k = c >> 1;
        int i = (c & 1) * 4096 + o * 256 + hw;
        Kq[((size_t)b * 8192 + i) * 16 + k] = __float2bfloat16(acc * SQRT_LOG2E);
    }
#pragma unroll
    for (int oo = 0; oo < 2; ++oo) {
        int o = g * 2 + oo;           // 0..31
        float a0 = b2[o], a1 = 0.f;
#pragma unroll
        for (int l = 0; l < 16; ++l) {
            a0 += W2s[o * 32 + l] * Xs[l][c];
            a1 += W2s[o * 32 + 16 + l] * Xs[16 + l][c];
        }
        float acc = a0 + a1;
        // position j = o*256 + hw, channel c; P-natural-order swizzle (v7):
        int jt = o * 8 + (hw >> 5);          // j >> 5
        int f  = (hw >> 4) & 1;              // frag: jl 0..15 -> 0, 16..31 -> 1
        int hh = (hw >> 2) & 1;              // owner half
        int idx = (hw & 3) | (((hw >> 3) & 1) << 2);
        Vswz[(size_t)b * 262144 + jt * 1024 + f * 512 + hh * 256 + c * 8 + idx] =
            __float2bfloat16(acc);
    }
}

// ---------------- Kernel B: flash attention, LDS-free, bf16 normalized partials ----------------
// v9 (post-mortem of v8): two i-tiles per wave REGRESSED (~+1.4us fill-normalized) —
// at the (256,4) cap, per-wave ILP and registers trade 1:1 (doubled acc+sc state ->
// spill/serialize). v9 = v7 inner loop EXACTLY (best measured, ~29.5us), but more
// RESIDENT WAVES instead of more chains per wave:
//   - __launch_bounds__(256, 5): reg cap 102; v7 live set ~86 -> fits, 5 waves/SIMD
//   - LSPLIT 3->4: 2048 blocks so 5 blocks/CU can actually be resident
// R6 arithmetic said latency-bound (553 cyc/slot vs ~160 busy); 4->5 chains/SIMD
// is the direct attack that does NOT touch per-wave register pressure.
// Keeps: P-natural V-swizzle (zero cross-lane ops), single accumulator, native x16
// MFMAs, depth-1 prefetch, streaming stores (NOT atomics: RMW pinned ~44us).
__global__ __launch_bounds__(256, 5) void flash_kernel(
    const __hip_bfloat16* __restrict__ Kq, const __hip_bfloat16* __restrict__ Vswz,
    __hip_bfloat16* __restrict__ Opart, float* __restrict__ Lpart)
{
    const int t = threadIdx.x;
    const int lane = t & 63;
    const int wv = t >> 6;            // 0..3
    const int m = lane & 31;
    const int h = lane >> 5;          // 0/1

    const int bid = blockIdx.x;
    const int s = bid & ((1 << LSPLIT) - 1);
    const int itile = (bid >> LSPLIT) & 63;
    const int b = bid >> (LSPLIT + 6);
    const int i0 = itile * 128 + wv * 32;
    const int niter = (8192 >> LSPLIT) >> 5;   // 16 tiles of 32 j
    const int jt0 = s * niter;

    const __hip_bfloat16* Kb = Kq + (size_t)b * 8192 * 16;
    const __hip_bfloat16* Vb = Vswz + (size_t)b * 262144 + h * 256 + m * 8;

    // Q B-frag (regs): B[k=8h+idx][n=m] = Kq[i0+m][8h+idx]
    const bf16x8 bq = *(const bf16x8*)(Kb + (size_t)(i0 + m) * 16 + h * 8);

    floatx16 oa = {};
    float l0 = 0.f, l1 = 0.f, l2 = 0.f, l3 = 0.f;

    // ---- software pipeline: preload tile jt0 ----
    bf16x8 ak = *(const bf16x8*)(Kb + (size_t)(jt0 * 32 + m) * 16 + h * 8);
    bf16x8 vb0 = *(const bf16x8*)(Vb + (size_t)jt0 * 1024 + 0);
    bf16x8 vb1 = *(const bf16x8*)(Vb + (size_t)jt0 * 1024 + 512);

#pragma unroll 2
    for (int it = 0; it < niter; ++it) {
        const bf16x8 cak = ak;
        const bf16x8 cv0 = vb0, cv1 = vb1;
        if (it + 1 < niter) {
            const int jn = jt0 + it + 1;
            ak  = *(const bf16x8*)(Kb + (size_t)(jn * 32 + m) * 16 + h * 8);
            vb0 = *(const bf16x8*)(Vb + (size_t)jn * 1024 + 0);
            vb1 = *(const bf16x8*)(Vb + (size_t)jn * 1024 + 512);
        }

        // S^T(32j x 32i) = K(A) x Q(B), K=16 exact
        floatx16 sc = __builtin_amdgcn_mfma_f32_32x32x16_bf16(cak, bq, (floatx16){}, 0, 0, 0);

        // P = 2^S ; sc reg 4g+idx holds j_loc = 8g+4h+idx, i = m.
        // cvt_pk pairs ARE the A-frag dwords under the v7 V-swizzle.
#pragma unroll
        for (int half = 0; half < 2; ++half) {
            u32x4 pau;
#pragma unroll
            for (int gg = 0; gg < 2; ++gg) {
                const int g = half * 2 + gg;
                float e0 = __builtin_amdgcn_exp2f(sc[4 * g + 0]);
                float e1 = __builtin_amdgcn_exp2f(sc[4 * g + 1]);
                float e2 = __builtin_amdgcn_exp2f(sc[4 * g + 2]);
                float e3 = __builtin_amdgcn_exp2f(sc[4 * g + 3]);
                l0 += e0; l1 += e1; l2 += e2; l3 += e3;
#if defined(__has_builtin) && __has_builtin(__builtin_amdgcn_cvt_pk_bf16_f32)
                bf16x2 pk0 = __builtin_amdgcn_cvt_pk_bf16_f32(e0, e1);
                bf16x2 pk1 = __builtin_amdgcn_cvt_pk_bf16_f32(e2, e3);
#else
                bf16x2 pk0 = {(__bf16)e0, (__bf16)e1};
                bf16x2 pk1 = {(__bf16)e2, (__bf16)e3};
#endif
                pau[gg * 2 + 0] = __builtin_bit_cast(unsigned, pk0);
                pau[gg * 2 + 1] = __builtin_bit_cast(unsigned, pk1);
            }
            bf16x8 pa = __builtin_bit_cast(bf16x8, pau);
            oa = __builtin_amdgcn_mfma_f32_32x32x16_bf16(pa, half ? cv1 : cv0, oa, 0, 0, 0);
        }
    }

    // full split-partial row-sum l_s for row i0+m (this lane's column)
    float l = (l0 + l1) + (l2 + l3);
    l += __shfl_xor(l, 32);
    const float rinv = __builtin_amdgcn_rcpf(l);

    // store normalized ratios r_s = O_s / l_s as bf16 (unit-scale, well-conditioned).
    // reg r -> row i_loc=(r&3)+8*(r>>2)+4h, col c=m ; l for row iloc lives in lane iloc
#pragma unroll
    for (int r = 0; r < 16; ++r) {
        int iloc = (r & 3) + 8 * (r >> 2) + 4 * h;
        float lr = __shfl(rinv, iloc);
        size_t row = (size_t)b * 8192 + i0 + iloc;
        Opart[((row << LSPLIT) | s) * 32 + m] = __float2bfloat16(oa[r] * lr);
    }
    if (h == 0)
        Lpart[(((size_t)b * 8192 + i0 + m) << LSPLIT) | s] = l;
}

// ---------------- Kernel C: weighted combine + epilogue ----------------
// out = (sum_s l_s * r_s) / (sum_s l_s) * gamma + in   (16 splits, LSPLIT=4)
__global__ __launch_bounds__(256) void combine_kernel(
    const unsigned short* __restrict__ Opart, const float* __restrict__ Lpart,
    const float* __restrict__ in, const float* __restrict__ gamma,
    float* __restrict__ out)
{
    const int gid = blockIdx.x * 256 + threadIdx.x;   // 0..262143
    const int row = gid >> 4;                          // 0..16383
    const int c2 = (gid & 15) * 2;
    const unsigned short* op = Opart + (((size_t)row << LSPLIT)) * 32 + c2;
    const float* lp = Lpart + ((size_t)row << LSPLIT);
    float ls[1 << LSPLIT];
#pragma unroll
    for (int q = 0; q < (1 << LSPLIT) / 4; ++q) {
        float4 lv = *(const float4*)(lp + q * 4);
        ls[q * 4 + 0] = lv.x; ls[q * 4 + 1] = lv.y;
        ls[q * 4 + 2] = lv.z; ls[q * 4 + 3] = lv.w;
    }
    float ax = 0.f, ay = 0.f;
    float lsum = 0.f;
#pragma unroll
    for (int s = 0; s < (1 << LSPLIT); ++s) {
        ushort2 u = *(const ushort2*)(op + s * 32);
        float l = ls[s];
        ax += l * __uint_as_float((unsigned)u.x << 16);
        ay += l * __uint_as_float((unsigned)u.y << 16);
        lsum += l;
    }
    const size_t base = (size_t)row * 32 + c2;
    float2 x = *(const float2*)(in + base);
    const float gl = gamma[0] / lsum;
    float2 r;
    r.x = ax * gl + x.x;
    r.y = ay * gl + x.y;
    *(float2*)(out + base) = r;
}

extern "C" void kernel_launch(void* const* d_in, const int* in_sizes, int n_in,
                              void* d_out, int out_size, void* d_ws, size_t ws_size,
                              hipStream_t stream) {
    const float* in = (const float*)d_in[0];
    const float* W1 = (const float*)d_in[1];
    const float* b1 = (const float*)d_in[2];
    const float* W2 = (const float*)d_in[3];
    const float* b2 = (const float*)d_in[4];
    const float* gamma = (const float*)d_in[5];
    float* out = (float*)d_out;

    __hip_bfloat16* Kq = (__hip_bfloat16*)d_ws;
    __hip_bfloat16* Vswz = Kq + KQ_ELEMS;
    __hip_bfloat16* Opart = (__hip_bfloat16*)((char*)d_ws + OPART_OFF);
    float* Lpart = (float*)(Opart + ((size_t)16384 << LSPLIT) * 32);

    proj_kernel<<<512, 512, 0, stream>>>(in, W1, b1, W2, b2, Kq, Vswz);
    flash_kernel<<<2 * 64 * (1 << LSPLIT), 256, 0, stream>>>(Kq, Vswz, Opart, Lpart);
    combine_kernel<<<1024, 256, 0, stream>>>((const unsigned short*)Opart, Lpart, in, gamma, out);
}

// Round 9
// 96.293 us; speedup vs baseline: 1.0311x; 1.0191x over previous
//
#include <hip/hip_runtime.h>
#include <hip/hip_bf16.h>
#include <math.h>

typedef __bf16 bf16x8 __attribute__((ext_vector_type(8)));
typedef __bf16 bf16x2 __attribute__((ext_vector_type(2)));
typedef float  floatx16 __attribute__((ext_vector_type(16)));
typedef unsigned u32x4 __attribute__((ext_vector_type(4)));

// Workspace layout (bytes):
//   Kq    bf16 [2][8192][16]        offset 0        (512 KB)  scaled by sqrt(log2 e)
//   Vswz  bf16 [2][8192][32]        offset 524288   (1 MB)    P-natural-order B-frag swizzle
//   Opart bf16 [2*8192][8][32]      offset 1572864  (8.4 MB)  normalized ratios r_s = O_s/l_s
//   Lpart f32  [2*8192][8]          after Opart     (512 KB)
#define KQ_ELEMS (2 * 8192 * 16)
#define OPART_OFF 1572864
#define SQRT_LOG2E 1.2011224087864498f
#define LSPLIT 3

// ---------------- Kernel A: projections ----------------
// v7 Vswz layout (verified): B-fragment in P's NATURAL slot order -> flash needs
// ZERO cross-lane ops. Per 32-j tile (f = jl>>4, jj = jl&15):
//   h = (jj>>2)&1 ; idx = (jj&3) | (((jj>>3)&1)<<2)
//   flat = jt*1024 + f*512 + h*256 + c*8 + idx
__global__ __launch_bounds__(512) void proj_kernel(
    const float* __restrict__ in, const float* __restrict__ W1,
    const float* __restrict__ b1, const float* __restrict__ W2,
    const float* __restrict__ b2,
    __hip_bfloat16* __restrict__ Kq, __hip_bfloat16* __restrict__ Vswz)
{
    __shared__ float Xs[32][32];
    __shared__ float W1s[16 * 32];
    __shared__ float W2s[32 * 32];
    const int t = threadIdx.x;
    const int bid = blockIdx.x;       // 0..511
    const int b = bid >> 8;
    const int hw = bid & 255;

    {
        int l = t >> 4, cs = (t & 15) * 2;
        float2 v = *(const float2*)(in + (((size_t)b * 32 + l) * 256 + hw) * 32 + cs);
        *(float2*)&Xs[l][cs] = v;
    }
    if (t < 128) *(float4*)&W1s[t * 4] = *(const float4*)(W1 + t * 4);
    if (t < 256) *(float4*)&W2s[t * 4] = *(const float4*)(W2 + t * 4);
    __syncthreads();

    const int c = t & 31;
    const int g = t >> 5;             // 0..15

    {
        int o = g;                    // 0..15
        float a0 = b1[o], a1 = 0.f;
#pragma unroll
        for (int l = 0; l < 16; ++l) {
            a0 += W1s[o * 32 + l] * Xs[l][c];
            a1 += W1s[o * 32 + 16 + l] * Xs[16 + l][c];
        }
        float acc = a0 + a1;
        int k = c >> 1;
        int i = (c & 1) * 4096 + o * 256 + hw;
        Kq[((size_t)b * 8192 + i) * 16 + k] = __float2bfloat16(acc * SQRT_LOG2E);
    }
#pragma unroll
    for (int oo = 0; oo < 2; ++oo) {
        int o = g * 2 + oo;           // 0..31
        float a0 = b2[o], a1 = 0.f;
#pragma unroll
        for (int l = 0; l < 16; ++l) {
            a0 += W2s[o * 32 + l] * Xs[l][c];
            a1 += W2s[o * 32 + 16 + l] * Xs[16 + l][c];
        }
        float acc = a0 + a1;
        // position j = o*256 + hw, channel c; P-natural-order swizzle (v7):
        int jt = o * 8 + (hw >> 5);          // j >> 5
        int f  = (hw >> 4) & 1;              // frag: jl 0..15 -> 0, 16..31 -> 1
        int hh = (hw >> 2) & 1;              // owner half
        int idx = (hw & 3) | (((hw >> 3) & 1) << 2);
        Vswz[(size_t)b * 262144 + jt * 1024 + f * 512 + hh * 256 + c * 8 + idx] =
            __float2bfloat16(acc);
    }
}

// ---------------- Kernel B: flash attention, LDS-free, bf16 normalized partials ----------------
// v10 (post-mortem of v7-v9): occupancy ladder plateaued (29.5 @4w, 28.5 @5w) at
// ~2.5x the VALU+trans issue floor -> per-wave chain latency is still exposed.
// R7 showed i-ILP doubles {bq, oa, sc} and spills. j-ILP is the cheap axis:
// TWO j-tiles per iteration share bq AND accumulate into the SAME oa — only
// +sc1 (16) and +1 in-flight K/V set (12) regs. Two independent S->exp->PV
// chains per wave = 8 chains/SIMD at 4 waves, live ~112 < 128 cap of (256,4).
// LSPLIT back to 3 (grid 1024 = 4 blk/CU suffices; halves combine traffic).
// Keeps: P-natural V-swizzle (zero cross-lane ops), single accumulator, native
// x16 MFMAs, pair-depth-1 prefetch, streaming stores (NOT atomics: ~44us pin).
__global__ __launch_bounds__(256, 4) void flash_kernel(
    const __hip_bfloat16* __restrict__ Kq, const __hip_bfloat16* __restrict__ Vswz,
    __hip_bfloat16* __restrict__ Opart, float* __restrict__ Lpart)
{
    const int t = threadIdx.x;
    const int lane = t & 63;
    const int wv = t >> 6;            // 0..3
    const int m = lane & 31;
    const int h = lane >> 5;          // 0/1

    const int bid = blockIdx.x;
    const int s = bid & ((1 << LSPLIT) - 1);
    const int itile = (bid >> LSPLIT) & 63;
    const int b = bid >> (LSPLIT + 6);
    const int i0 = itile * 128 + wv * 32;
    const int niter = (8192 >> LSPLIT) >> 5;   // 32 tiles of 32 j
    const int npair = niter >> 1;              // 16 pairs
    const int jt0 = s * niter;

    const __hip_bfloat16* Kb = Kq + (size_t)b * 8192 * 16;
    const __hip_bfloat16* Vb = Vswz + (size_t)b * 262144 + h * 256 + m * 8;

    // Q B-frag (regs): B[k=8h+idx][n=m] = Kq[i0+m][8h+idx]
    const bf16x8 bq = *(const bf16x8*)(Kb + (size_t)(i0 + m) * 16 + h * 8);

    floatx16 oa = {};
    float l0 = 0.f, l1 = 0.f, l2 = 0.f, l3 = 0.f;

    // ---- software pipeline: preload pair 0 (tiles jt0, jt0+1) ----
    bf16x8 ak0 = *(const bf16x8*)(Kb + (size_t)(jt0 * 32 + m) * 16 + h * 8);
    bf16x8 ak1 = *(const bf16x8*)(Kb + (size_t)((jt0 + 1) * 32 + m) * 16 + h * 8);
    bf16x8 va0 = *(const bf16x8*)(Vb + (size_t)jt0 * 1024 + 0);
    bf16x8 va1 = *(const bf16x8*)(Vb + (size_t)jt0 * 1024 + 512);
    bf16x8 vc0 = *(const bf16x8*)(Vb + (size_t)(jt0 + 1) * 1024 + 0);
    bf16x8 vc1 = *(const bf16x8*)(Vb + (size_t)(jt0 + 1) * 1024 + 512);

#pragma unroll 1
    for (int ip = 0; ip < npair; ++ip) {
        const bf16x8 cak0 = ak0, cak1 = ak1;
        const bf16x8 cva0 = va0, cva1 = va1, cvc0 = vc0, cvc1 = vc1;
        if (ip + 1 < npair) {
            const int jn = jt0 + 2 * (ip + 1);
            ak0 = *(const bf16x8*)(Kb + (size_t)(jn * 32 + m) * 16 + h * 8);
            ak1 = *(const bf16x8*)(Kb + (size_t)((jn + 1) * 32 + m) * 16 + h * 8);
            va0 = *(const bf16x8*)(Vb + (size_t)jn * 1024 + 0);
            va1 = *(const bf16x8*)(Vb + (size_t)jn * 1024 + 512);
            vc0 = *(const bf16x8*)(Vb + (size_t)(jn + 1) * 1024 + 0);
            vc1 = *(const bf16x8*)(Vb + (size_t)(jn + 1) * 1024 + 512);
        }

        // Two independent S chains: S^T(32j x 32i) = K(A) x Q(B), K=16 exact
        floatx16 sc0 = __builtin_amdgcn_mfma_f32_32x32x16_bf16(cak0, bq, (floatx16){}, 0, 0, 0);
        floatx16 sc1 = __builtin_amdgcn_mfma_f32_32x32x16_bf16(cak1, bq, (floatx16){}, 0, 0, 0);

        // P = 2^S ; cvt_pk pairs ARE the A-frag dwords under the v7 V-swizzle.
#pragma unroll
        for (int half = 0; half < 2; ++half) {
            u32x4 pau;
#pragma unroll
            for (int gg = 0; gg < 2; ++gg) {
                const int g = half * 2 + gg;
                float e0 = __builtin_amdgcn_exp2f(sc0[4 * g + 0]);
                float e1 = __builtin_amdgcn_exp2f(sc0[4 * g + 1]);
                float e2 = __builtin_amdgcn_exp2f(sc0[4 * g + 2]);
                float e3 = __builtin_amdgcn_exp2f(sc0[4 * g + 3]);
                l0 += e0; l1 += e1; l2 += e2; l3 += e3;
#if defined(__has_builtin) && __has_builtin(__builtin_amdgcn_cvt_pk_bf16_f32)
                bf16x2 pk0 = __builtin_amdgcn_cvt_pk_bf16_f32(e0, e1);
                bf16x2 pk1 = __builtin_amdgcn_cvt_pk_bf16_f32(e2, e3);
#else
                bf16x2 pk0 = {(__bf16)e0, (__bf16)e1};
                bf16x2 pk1 = {(__bf16)e2, (__bf16)e3};
#endif
                pau[gg * 2 + 0] = __builtin_bit_cast(unsigned, pk0);
                pau[gg * 2 + 1] = __builtin_bit_cast(unsigned, pk1);
            }
            bf16x8 pa = __builtin_bit_cast(bf16x8, pau);
            oa = __builtin_amdgcn_mfma_f32_32x32x16_bf16(pa, half ? cva1 : cva0, oa, 0, 0, 0);
        }
#pragma unroll
        for (int half = 0; half < 2; ++half) {
            u32x4 pau;
#pragma unroll
            for (int gg = 0; gg < 2; ++gg) {
                const int g = half * 2 + gg;
                float e0 = __builtin_amdgcn_exp2f(sc1[4 * g + 0]);
                float e1 = __builtin_amdgcn_exp2f(sc1[4 * g + 1]);
                float e2 = __builtin_amdgcn_exp2f(sc1[4 * g + 2]);
                float e3 = __builtin_amdgcn_exp2f(sc1[4 * g + 3]);
                l0 += e0; l1 += e1; l2 += e2; l3 += e3;
#if defined(__has_builtin) && __has_builtin(__builtin_amdgcn_cvt_pk_bf16_f32)
                bf16x2 pk0 = __builtin_amdgcn_cvt_pk_bf16_f32(e0, e1);
                bf16x2 pk1 = __builtin_amdgcn_cvt_pk_bf16_f32(e2, e3);
#else
                bf16x2 pk0 = {(__bf16)e0, (__bf16)e1};
                bf16x2 pk1 = {(__bf16)e2, (__bf16)e3};
#endif
                pau[gg * 2 + 0] = __builtin_bit_cast(unsigned, pk0);
                pau[gg * 2 + 1] = __builtin_bit_cast(unsigned, pk1);
            }
            bf16x8 pa = __builtin_bit_cast(bf16x8, pau);
            oa = __builtin_amdgcn_mfma_f32_32x32x16_bf16(pa, half ? cvc1 : cvc0, oa, 0, 0, 0);
        }
    }

    // full split-partial row-sum l_s for row i0+m (this lane's column)
    float l = (l0 + l1) + (l2 + l3);
    l += __shfl_xor(l, 32);
    const float rinv = __builtin_amdgcn_rcpf(l);

    // store normalized ratios r_s = O_s / l_s as bf16 (unit-scale, well-conditioned).
    // reg r -> row i_loc=(r&3)+8*(r>>2)+4h, col c=m ; l for row iloc lives in lane iloc
#pragma unroll
    for (int r = 0; r < 16; ++r) {
        int iloc = (r & 3) + 8 * (r >> 2) + 4 * h;
        float lr = __shfl(rinv, iloc);
        size_t row = (size_t)b * 8192 + i0 + iloc;
        Opart[((row << LSPLIT) | s) * 32 + m] = __float2bfloat16(oa[r] * lr);
    }
    if (h == 0)
        Lpart[(((size_t)b * 8192 + i0 + m) << LSPLIT) | s] = l;
}

// ---------------- Kernel C: weighted combine + epilogue ----------------
// out = (sum_s l_s * r_s) / (sum_s l_s) * gamma + in   (8 splits, LSPLIT=3)
__global__ __launch_bounds__(256) void combine_kernel(
    const unsigned short* __restrict__ Opart, const float* __restrict__ Lpart,
    const float* __restrict__ in, const float* __restrict__ gamma,
    float* __restrict__ out)
{
    const int gid = blockIdx.x * 256 + threadIdx.x;   // 0..262143
    const int row = gid >> 4;                          // 0..16383
    const int c2 = (gid & 15) * 2;
    const unsigned short* op = Opart + (((size_t)row << LSPLIT)) * 32 + c2;
    const float* lp = Lpart + ((size_t)row << LSPLIT);
    float ls[1 << LSPLIT];
#pragma unroll
    for (int q = 0; q < (1 << LSPLIT) / 4; ++q) {
        float4 lv = *(const float4*)(lp + q * 4);
        ls[q * 4 + 0] = lv.x; ls[q * 4 + 1] = lv.y;
        ls[q * 4 + 2] = lv.z; ls[q * 4 + 3] = lv.w;
    }
    float ax = 0.f, ay = 0.f;
    float lsum = 0.f;
#pragma unroll
    for (int s = 0; s < (1 << LSPLIT); ++s) {
        ushort2 u = *(const ushort2*)(op + s * 32);
        float l = ls[s];
        ax += l * __uint_as_float((unsigned)u.x << 16);
        ay += l * __uint_as_float((unsigned)u.y << 16);
        lsum += l;
    }
    const size_t base = (size_t)row * 32 + c2;
    float2 x = *(const float2*)(in + base);
    const float gl = gamma[0] / lsum;
    float2 r;
    r.x = ax * gl + x.x;
    r.y = ay * gl + x.y;
    *(float2*)(out + base) = r;
}

extern "C" void kernel_launch(void* const* d_in, const int* in_sizes, int n_in,
                              void* d_out, int out_size, void* d_ws, size_t ws_size,
                              hipStream_t stream) {
    const float* in = (const float*)d_in[0];
    const float* W1 = (const float*)d_in[1];
    const float* b1 = (const float*)d_in[2];
    const float* W2 = (const float*)d_in[3];
    const float* b2 = (const float*)d_in[4];
    const float* gamma = (const float*)d_in[5];
    float* out = (float*)d_out;

    __hip_bfloat16* Kq = (__hip_bfloat16*)d_ws;
    __hip_bfloat16* Vswz = Kq + KQ_ELEMS;
    __hip_bfloat16* Opart = (__hip_bfloat16*)((char*)d_ws + OPART_OFF);
    float* Lpart = (float*)(Opart + ((size_t)16384 << LSPLIT) * 32);

    proj_kernel<<<512, 512, 0, stream>>>(in, W1, b1, W2, b2, Kq, Vswz);
    flash_kernel<<<2 * 64 * (1 << LSPLIT), 256, 0, stream>>>(Kq, Vswz, Opart, Lpart);
    combine_kernel<<<1024, 256, 0, stream>>>((const unsigned short*)Opart, Lpart, in, gamma, out);
}

// Round 10
// 95.316 us; speedup vs baseline: 1.0417x; 1.0103x over previous
//
#include <hip/hip_runtime.h>
#include <hip/hip_bf16.h>
#include <math.h>

typedef __bf16 bf16x8 __attribute__((ext_vector_type(8)));
typedef __bf16 bf16x2 __attribute__((ext_vector_type(2)));
typedef float  floatx16 __attribute__((ext_vector_type(16)));
typedef unsigned u32x4 __attribute__((ext_vector_type(4)));

// Workspace layout (bytes):
//   Kq    bf16 [2][8192][16]        offset 0        (512 KB)  scaled by sqrt(log2 e)
//   Vswz  bf16 [2][8192][32]        offset 524288   (1 MB)    P-natural-order B-frag swizzle
//   Opart bf16 [2*8192][8][32]      offset 1572864  (8.4 MB)  normalized ratios r_s = O_s/l_s
//   Lpart f32  [2*8192][8]          after Opart     (512 KB)
#define KQ_ELEMS (2 * 8192 * 16)
#define OPART_OFF 1572864
#define SQRT_LOG2E 1.2011224087864498f
#define LSPLIT 3

// ---------------- Kernel A: projections ----------------
// v7 Vswz layout (verified): B-fragment in P's NATURAL slot order -> flash needs
// ZERO cross-lane ops. Per 32-j tile (f = jl>>4, jj = jl&15):
//   h = (jj>>2)&1 ; idx = (jj&3) | (((jj>>3)&1)<<2)
//   flat = jt*1024 + f*512 + h*256 + c*8 + idx
__global__ __launch_bounds__(512) void proj_kernel(
    const float* __restrict__ in, const float* __restrict__ W1,
    const float* __restrict__ b1, const float* __restrict__ W2,
    const float* __restrict__ b2,
    __hip_bfloat16* __restrict__ Kq, __hip_bfloat16* __restrict__ Vswz)
{
    __shared__ float Xs[32][32];
    __shared__ float W1s[16 * 32];
    __shared__ float W2s[32 * 32];
    const int t = threadIdx.x;
    const int bid = blockIdx.x;       // 0..511
    const int b = bid >> 8;
    const int hw = bid & 255;

    {
        int l = t >> 4, cs = (t & 15) * 2;
        float2 v = *(const float2*)(in + (((size_t)b * 32 + l) * 256 + hw) * 32 + cs);
        *(float2*)&Xs[l][cs] = v;
    }
    if (t < 128) *(float4*)&W1s[t * 4] = *(const float4*)(W1 + t * 4);
    if (t < 256) *(float4*)&W2s[t * 4] = *(const float4*)(W2 + t * 4);
    __syncthreads();

    const int c = t & 31;
    const int g = t >> 5;             // 0..15

    {
        int o = g;                    // 0..15
        float a0 = b1[o], a1 = 0.f;
#pragma unroll
        for (int l = 0; l < 16; ++l) {
            a0 += W1s[o * 32 + l] * Xs[l][c];
            a1 += W1s[o * 32 + 16 + l] * Xs[16 + l][c];
        }
        float acc = a0 + a1;
        int k = c >> 1;
        int i = (c & 1) * 4096 + o * 256 + hw;
        Kq[((size_t)b * 8192 + i) * 16 + k] = __float2bfloat16(acc * SQRT_LOG2E);
    }
#pragma unroll
    for (int oo = 0; oo < 2; ++oo) {
        int o = g * 2 + oo;           // 0..31
        float a0 = b2[o], a1 = 0.f;
#pragma unroll
        for (int l = 0; l < 16; ++l) {
            a0 += W2s[o * 32 + l] * Xs[l][c];
            a1 += W2s[o * 32 + 16 + l] * Xs[16 + l][c];
        }
        float acc = a0 + a1;
        // position j = o*256 + hw, channel c; P-natural-order swizzle (v7):
        int jt = o * 8 + (hw >> 5);          // j >> 5
        int f  = (hw >> 4) & 1;              // frag: jl 0..15 -> 0, 16..31 -> 1
        int hh = (hw >> 2) & 1;              // owner half
        int idx = (hw & 3) | (((hw >> 3) & 1) << 2);
        Vswz[(size_t)b * 262144 + jt * 1024 + f * 512 + hh * 256 + c * 8 + idx] =
            __float2bfloat16(acc);
    }
}

// ---------------- Kernel B: flash attention, LDS-free, bf16 normalized partials ----------------
// v11 (post-mortem of v8-v10): all ILP/occupancy levers since v7 were null
// (28.5-30.6us); per-slot service time is occupancy-INVARIANT (~540 cyc/wave-iter
// at 4 and 5 waves) -> a shared stall, likely the vmcnt wait: depth-1 prefetch
// gives loads only ~1 iteration (~550cy) of slack vs loaded-L2 latency. v11 =
// EXACT v7/R6 inner loop (best measured: 29.5us flash, 95.3 total) + DEPTH-2
// prefetch via even/odd register sets (A computes tile 2ip, then reloads for
// 2ip+2 -> ~2 iterations of slack, no copies, +12 in-flight regs, live ~100 <
// 128 cap). LSPLIT=3 (R6 best). Keeps: P-natural V-swizzle (zero cross-lane),
// single accumulator, native x16 MFMAs, streaming stores (NOT atomics).
__global__ __launch_bounds__(256, 4) void flash_kernel(
    const __hip_bfloat16* __restrict__ Kq, const __hip_bfloat16* __restrict__ Vswz,
    __hip_bfloat16* __restrict__ Opart, float* __restrict__ Lpart)
{
    const int t = threadIdx.x;
    const int lane = t & 63;
    const int wv = t >> 6;            // 0..3
    const int m = lane & 31;
    const int h = lane >> 5;          // 0/1

    const int bid = blockIdx.x;
    const int s = bid & ((1 << LSPLIT) - 1);
    const int itile = (bid >> LSPLIT) & 63;
    const int b = bid >> (LSPLIT + 6);
    const int i0 = itile * 128 + wv * 32;
    const int niter = (8192 >> LSPLIT) >> 5;   // 32 tiles of 32 j
    const int npair = niter >> 1;              // 16 pairs
    const int jt0 = s * niter;

    const __hip_bfloat16* Kb = Kq + (size_t)b * 8192 * 16;
    const __hip_bfloat16* Vb = Vswz + (size_t)b * 262144 + h * 256 + m * 8;

    // Q B-frag (regs): B[k=8h+idx][n=m] = Kq[i0+m][8h+idx]
    const bf16x8 bq = *(const bf16x8*)(Kb + (size_t)(i0 + m) * 16 + h * 8);

    floatx16 oa = {};
    float l0 = 0.f, l1 = 0.f, l2 = 0.f, l3 = 0.f;

    // ---- software pipeline depth 2: preload tiles jt0 (set A) and jt0+1 (set B) ----
    bf16x8 akA = *(const bf16x8*)(Kb + (size_t)(jt0 * 32 + m) * 16 + h * 8);
    bf16x8 vA0 = *(const bf16x8*)(Vb + (size_t)jt0 * 1024 + 0);
    bf16x8 vA1 = *(const bf16x8*)(Vb + (size_t)jt0 * 1024 + 512);
    bf16x8 akB = *(const bf16x8*)(Kb + (size_t)(jt0 + 1) * 32 * 16 + (size_t)m * 16 + h * 8);
    bf16x8 vB0 = *(const bf16x8*)(Vb + (size_t)(jt0 + 1) * 1024 + 0);
    bf16x8 vB1 = *(const bf16x8*)(Vb + (size_t)(jt0 + 1) * 1024 + 512);

#pragma unroll 1
    for (int ip = 0; ip < npair; ++ip) {
        // ---- tile 2*ip from set A ----
        {
            floatx16 sc = __builtin_amdgcn_mfma_f32_32x32x16_bf16(akA, bq, (floatx16){}, 0, 0, 0);
#pragma unroll
            for (int half = 0; half < 2; ++half) {
                u32x4 pau;
#pragma unroll
                for (int gg = 0; gg < 2; ++gg) {
                    const int g = half * 2 + gg;
                    float e0 = __builtin_amdgcn_exp2f(sc[4 * g + 0]);
                    float e1 = __builtin_amdgcn_exp2f(sc[4 * g + 1]);
                    float e2 = __builtin_amdgcn_exp2f(sc[4 * g + 2]);
                    float e3 = __builtin_amdgcn_exp2f(sc[4 * g + 3]);
                    l0 += e0; l1 += e1; l2 += e2; l3 += e3;
#if defined(__has_builtin) && __has_builtin(__builtin_amdgcn_cvt_pk_bf16_f32)
                    bf16x2 pk0 = __builtin_amdgcn_cvt_pk_bf16_f32(e0, e1);
                    bf16x2 pk1 = __builtin_amdgcn_cvt_pk_bf16_f32(e2, e3);
#else
                    bf16x2 pk0 = {(__bf16)e0, (__bf16)e1};
                    bf16x2 pk1 = {(__bf16)e2, (__bf16)e3};
#endif
                    pau[gg * 2 + 0] = __builtin_bit_cast(unsigned, pk0);
                    pau[gg * 2 + 1] = __builtin_bit_cast(unsigned, pk1);
                }
                bf16x8 pa = __builtin_bit_cast(bf16x8, pau);
                oa = __builtin_amdgcn_mfma_f32_32x32x16_bf16(pa, half ? vA1 : vA0, oa, 0, 0, 0);
            }
            // reload set A for tile 2*ip+2 (consumed ~2 iterations from now)
            if (ip + 1 < npair) {
                const int jn = jt0 + 2 * ip + 2;
                akA = *(const bf16x8*)(Kb + (size_t)(jn * 32 + m) * 16 + h * 8);
                vA0 = *(const bf16x8*)(Vb + (size_t)jn * 1024 + 0);
                vA1 = *(const bf16x8*)(Vb + (size_t)jn * 1024 + 512);
            }
        }
        // ---- tile 2*ip+1 from set B ----
        {
            floatx16 sc = __builtin_amdgcn_mfma_f32_32x32x16_bf16(akB, bq, (floatx16){}, 0, 0, 0);
#pragma unroll
            for (int half = 0; half < 2; ++half) {
                u32x4 pau;
#pragma unroll
                for (int gg = 0; gg < 2; ++gg) {
                    const int g = half * 2 + gg;
                    float e0 = __builtin_amdgcn_exp2f(sc[4 * g + 0]);
                    float e1 = __builtin_amdgcn_exp2f(sc[4 * g + 1]);
                    float e2 = __builtin_amdgcn_exp2f(sc[4 * g + 2]);
                    float e3 = __builtin_amdgcn_exp2f(sc[4 * g + 3]);
                    l0 += e0; l1 += e1; l2 += e2; l3 += e3;
#if defined(__has_builtin) && __has_builtin(__builtin_amdgcn_cvt_pk_bf16_f32)
                    bf16x2 pk0 = __builtin_amdgcn_cvt_pk_bf16_f32(e0, e1);
                    bf16x2 pk1 = __builtin_amdgcn_cvt_pk_bf16_f32(e2, e3);
#else
                    bf16x2 pk0 = {(__bf16)e0, (__bf16)e1};
                    bf16x2 pk1 = {(__bf16)e2, (__bf16)e3};
#endif
                    pau[gg * 2 + 0] = __builtin_bit_cast(unsigned, pk0);
                    pau[gg * 2 + 1] = __builtin_bit_cast(unsigned, pk1);
                }
                bf16x8 pa = __builtin_bit_cast(bf16x8, pau);
                oa = __builtin_amdgcn_mfma_f32_32x32x16_bf16(pa, half ? vB1 : vB0, oa, 0, 0, 0);
            }
            // reload set B for tile 2*ip+3
            if (ip + 1 < npair) {
                const int jn = jt0 + 2 * ip + 3;
                akB = *(const bf16x8*)(Kb + (size_t)(jn * 32 + m) * 16 + h * 8);
                vB0 = *(const bf16x8*)(Vb + (size_t)jn * 1024 + 0);
                vB1 = *(const bf16x8*)(Vb + (size_t)jn * 1024 + 512);
            }
        }
    }

    // full split-partial row-sum l_s for row i0+m (this lane's column)
    float l = (l0 + l1) + (l2 + l3);
    l += __shfl_xor(l, 32);
    const float rinv = __builtin_amdgcn_rcpf(l);

    // store normalized ratios r_s = O_s / l_s as bf16 (unit-scale, well-conditioned).
    // reg r -> row i_loc=(r&3)+8*(r>>2)+4h, col c=m ; l for row iloc lives in lane iloc
#pragma unroll
    for (int r = 0; r < 16; ++r) {
        int iloc = (r & 3) + 8 * (r >> 2) + 4 * h;
        float lr = __shfl(rinv, iloc);
        size_t row = (size_t)b * 8192 + i0 + iloc;
        Opart[((row << LSPLIT) | s) * 32 + m] = __float2bfloat16(oa[r] * lr);
    }
    if (h == 0)
        Lpart[(((size_t)b * 8192 + i0 + m) << LSPLIT) | s] = l;
}

// ---------------- Kernel C: weighted combine + epilogue ----------------
// out = (sum_s l_s * r_s) / (sum_s l_s) * gamma + in   (8 splits, LSPLIT=3)
__global__ __launch_bounds__(256) void combine_kernel(
    const unsigned short* __restrict__ Opart, const float* __restrict__ Lpart,
    const float* __restrict__ in, const float* __restrict__ gamma,
    float* __restrict__ out)
{
    const int gid = blockIdx.x * 256 + threadIdx.x;   // 0..262143
    const int row = gid >> 4;                          // 0..16383
    const int c2 = (gid & 15) * 2;
    const unsigned short* op = Opart + (((size_t)row << LSPLIT)) * 32 + c2;
    const float* lp = Lpart + ((size_t)row << LSPLIT);
    float4 l0 = *(const float4*)(lp);
    float4 l1 = *(const float4*)(lp + 4);
    float ls8[8] = {l0.x, l0.y, l0.z, l0.w, l1.x, l1.y, l1.z, l1.w};
    float ax = 0.f, ay = 0.f;
    float lsum = 0.f;
#pragma unroll
    for (int s = 0; s < (1 << LSPLIT); ++s) {
        ushort2 u = *(const ushort2*)(op + s * 32);
        float ls = ls8[s];
        ax += ls * __uint_as_float((unsigned)u.x << 16);
        ay += ls * __uint_as_float((unsigned)u.y << 16);
        lsum += ls;
    }
    const size_t base = (size_t)row * 32 + c2;
    float2 x = *(const float2*)(in + base);
    const float gl = gamma[0] / lsum;
    float2 r;
    r.x = ax * gl + x.x;
    r.y = ay * gl + x.y;
    *(float2*)(out + base) = r;
}

extern "C" void kernel_launch(void* const* d_in, const int* in_sizes, int n_in,
                              void* d_out, int out_size, void* d_ws, size_t ws_size,
                              hipStream_t stream) {
    const float* in = (const float*)d_in[0];
    const float* W1 = (const float*)d_in[1];
    const float* b1 = (const float*)d_in[2];
    const float* W2 = (const float*)d_in[3];
    const float* b2 = (const float*)d_in[4];
    const float* gamma = (const float*)d_in[5];
    float* out = (float*)d_out;

    __hip_bfloat16* Kq = (__hip_bfloat16*)d_ws;
    __hip_bfloat16* Vswz = Kq + KQ_ELEMS;
    __hip_bfloat16* Opart = (__hip_bfloat16*)((char*)d_ws + OPART_OFF);
    float* Lpart = (float*)(Opart + ((size_t)16384 << LSPLIT) * 32);

    proj_kernel<<<512, 512, 0, stream>>>(in, W1, b1, W2, b2, Kq, Vswz);
    flash_kernel<<<2 * 64 * (1 << LSPLIT), 256, 0, stream>>>(Kq, Vswz, Opart, Lpart);
    combine_kernel<<<1024, 256, 0, stream>>>((const unsigned short*)Opart, Lpart, in, gamma, out);
}